// Round 1
// baseline (3003.776 us; speedup 1.0000x reference)
//
#include <hip/hip_runtime.h>
#include <stdint.h>

// Problem constants (B=2, S=1024, H=4096, NH=32, G=2, D=128, HG=16)
#define S_LEN 1024
#define HDIM  4096
#define BS    2048          // B * S
#define DHEAD 128
#define HPG   16            // heads per group
#define QKV_N 4608          // 4096 (q) + 256 (k) + 256 (v)
#define FFN   16384

typedef __attribute__((ext_vector_type(8))) short bf16x8;
typedef __attribute__((ext_vector_type(4))) float f32x4;
typedef __attribute__((ext_vector_type(4))) unsigned short u16x4;

__device__ __forceinline__ unsigned short f2bf(float f) {
  union { float f; unsigned u; } c; c.f = f;
  return (unsigned short)((c.u + 0x7fffu + ((c.u >> 16) & 1u)) >> 16);  // RNE
}

// ---------------------------------------------------------------------------
// out = res + LN(inp)*g + b ; optional fp32 and bf16 outputs
// ---------------------------------------------------------------------------
__global__ __launch_bounds__(256) void ln_res_kernel(
    const float* __restrict__ res, const float* __restrict__ inp,
    const float* __restrict__ gam, const float* __restrict__ bet,
    float* __restrict__ of, unsigned short* __restrict__ ob)
{
  const int row = blockIdx.x;
  const int tid = threadIdx.x;
  const float* ip = inp + (size_t)row * HDIM;
  const float* rp = res + (size_t)row * HDIM;

  float4 xv[4];
  float s = 0.f, ss = 0.f;
#pragma unroll
  for (int i = 0; i < 4; ++i) {
    xv[i] = *(const float4*)(ip + ((i * 256 + tid) << 2));
    s  += xv[i].x + xv[i].y + xv[i].z + xv[i].w;
    ss += xv[i].x * xv[i].x + xv[i].y * xv[i].y + xv[i].z * xv[i].z + xv[i].w * xv[i].w;
  }
#pragma unroll
  for (int off = 32; off; off >>= 1) {
    s  += __shfl_xor(s, off);
    ss += __shfl_xor(ss, off);
  }
  __shared__ float red[8];
  if ((tid & 63) == 0) { red[(tid >> 6) * 2] = s; red[(tid >> 6) * 2 + 1] = ss; }
  __syncthreads();
  s  = red[0] + red[2] + red[4] + red[6];
  ss = red[1] + red[3] + red[5] + red[7];
  const float mu   = s * (1.f / HDIM);
  const float rstd = rsqrtf(ss * (1.f / HDIM) - mu * mu + 1e-5f);

#pragma unroll
  for (int i = 0; i < 4; ++i) {
    const int e = (i * 256 + tid) << 2;
    const float4 gv = *(const float4*)(gam + e);
    const float4 bv = *(const float4*)(bet + e);
    const float4 rv = *(const float4*)(rp + e);
    float4 o;
    o.x = rv.x + (xv[i].x - mu) * rstd * gv.x + bv.x;
    o.y = rv.y + (xv[i].y - mu) * rstd * gv.y + bv.y;
    o.z = rv.z + (xv[i].z - mu) * rstd * gv.z + bv.z;
    o.w = rv.w + (xv[i].w - mu) * rstd * gv.w + bv.w;
    if (of) *(float4*)(of + (size_t)row * HDIM + e) = o;
    if (ob) {
      u16x4 pk; pk.x = f2bf(o.x); pk.y = f2bf(o.y); pk.z = f2bf(o.z); pk.w = f2bf(o.w);
      *(u16x4*)(ob + (size_t)row * HDIM + e) = pk;
    }
  }
}

// ---------------------------------------------------------------------------
// W [K][N] fp32  ->  Wt [N][K] bf16   (32x32 tiles via LDS)
// ---------------------------------------------------------------------------
__global__ __launch_bounds__(256) void transpose_cvt_kernel(
    const float* __restrict__ W, unsigned short* __restrict__ Wt,
    const int K, const int N)
{
  __shared__ float t[32][36];                 // 36: 16B-aligned rows, spread banks
  const int n0 = blockIdx.x << 5, k0 = blockIdx.y << 5;
  const int tx4 = threadIdx.x & 7, ty = threadIdx.x >> 3;
  const float4 v4 = *(const float4*)(W + (size_t)(k0 + ty) * N + n0 + (tx4 << 2));
  *(float4*)&t[ty][tx4 << 2] = v4;
  __syncthreads();
  u16x4 o;
  o.x = f2bf(t[(tx4 << 2) + 0][ty]);
  o.y = f2bf(t[(tx4 << 2) + 1][ty]);
  o.z = f2bf(t[(tx4 << 2) + 2][ty]);
  o.w = f2bf(t[(tx4 << 2) + 3][ty]);
  *(u16x4*)(Wt + (size_t)(n0 + ty) * K + k0 + (tx4 << 2)) = o;
}

__global__ __launch_bounds__(256) void pack_bias_kernel(
    const float* __restrict__ bq, const float* __restrict__ bk,
    const float* __restrict__ bv, float* __restrict__ out)
{
  const int i = blockIdx.x * 256 + threadIdx.x;   // 4608 total
  float v;
  if (i < 4096)       v = bq[i];
  else if (i < 4352)  v = bk[i - 4096];
  else                v = bv[i - 4352];
  out[i] = v;
}

// ---------------------------------------------------------------------------
// C[M][N] = A[M][K] @ Bt[N][K]^T + bias ; optional GELU ; fp32/bf16 stores
// 128x128 tile, BK=32, 4 waves (2x2), 4x4 16x16x32 MFMA frags per wave.
// ---------------------------------------------------------------------------
template<int DO_GELU, int ST_F32, int ST_BF16>
__global__ __launch_bounds__(256) void gemm_kernel(
    const unsigned short* __restrict__ A,
    const unsigned short* __restrict__ Bt,
    const float* __restrict__ bias,
    float* __restrict__ Cf, unsigned short* __restrict__ Cb,
    const int M, const int N, const int K)
{
  __shared__ unsigned short As[128 * 32];
  __shared__ unsigned short Bs[128 * 32];
  const int tid  = threadIdx.x;
  const int lane = tid & 63;
  const int w = tid >> 6, wm = w >> 1, wn = w & 1;
  const int bm = blockIdx.y << 7, bn = blockIdx.x << 7;
  const int fr = lane & 15, kq = lane >> 4;

  const unsigned short* Ag = A  + (size_t)bm * K;
  const unsigned short* Bg = Bt + (size_t)bn * K;
  const int r0 = tid >> 2, k0e = (tid & 3) << 3;   // 16B chunk per thread
  const int r1 = r0 + 64;

  f32x4 acc[4][4] = {};

  bf16x8 ra0 = *(const bf16x8*)(Ag + (size_t)r0 * K + k0e);
  bf16x8 ra1 = *(const bf16x8*)(Ag + (size_t)r1 * K + k0e);
  bf16x8 rb0 = *(const bf16x8*)(Bg + (size_t)r0 * K + k0e);
  bf16x8 rb1 = *(const bf16x8*)(Bg + (size_t)r1 * K + k0e);

  const int KT = K >> 5;
  for (int kt = 0; kt < KT; ++kt) {
    __syncthreads();
    *(bf16x8*)(As + r0 * 32 + k0e) = ra0;
    *(bf16x8*)(As + r1 * 32 + k0e) = ra1;
    *(bf16x8*)(Bs + r0 * 32 + k0e) = rb0;
    *(bf16x8*)(Bs + r1 * 32 + k0e) = rb1;
    if (kt + 1 < KT) {
      const int ko = (kt + 1) << 5;
      ra0 = *(const bf16x8*)(Ag + (size_t)r0 * K + ko + k0e);
      ra1 = *(const bf16x8*)(Ag + (size_t)r1 * K + ko + k0e);
      rb0 = *(const bf16x8*)(Bg + (size_t)r0 * K + ko + k0e);
      rb1 = *(const bf16x8*)(Bg + (size_t)r1 * K + ko + k0e);
    }
    __syncthreads();

    bf16x8 af[4], bfr[4];
#pragma unroll
    for (int i = 0; i < 4; ++i) {
      af[i]  = *(const bf16x8*)(As + (wm * 64 + i * 16 + fr) * 32 + (kq << 3));
      bfr[i] = *(const bf16x8*)(Bs + (wn * 64 + i * 16 + fr) * 32 + (kq << 3));
    }
#pragma unroll
    for (int mi = 0; mi < 4; ++mi)
#pragma unroll
      for (int ni = 0; ni < 4; ++ni)
        acc[mi][ni] = __builtin_amdgcn_mfma_f32_16x16x32_bf16(af[mi], bfr[ni], acc[mi][ni], 0, 0, 0);
  }

#pragma unroll
  for (int mi = 0; mi < 4; ++mi) {
#pragma unroll
    for (int ni = 0; ni < 4; ++ni) {
      const int col = bn + wn * 64 + ni * 16 + fr;
      const float bv = bias[col];
#pragma unroll
      for (int r = 0; r < 4; ++r) {
        const int row = bm + wm * 64 + mi * 16 + kq * 4 + r;
        float v = acc[mi][ni][r] + bv;
        if (DO_GELU) v = 0.5f * v * (1.f + erff(v * 0.7071067811865476f));
        if (ST_F32)  Cf[(size_t)row * N + col] = v;
        if (ST_BF16) Cb[(size_t)row * N + col] = f2bf(v);
      }
    }
  }
}

// ---------------------------------------------------------------------------
// Causal GQA flash attention, fp32 math. One block = (b, g, h, 64-row q tile).
// 4 waves x 16 rows. K/Q fp32 in LDS (XOR-swizzled 16B chunks), V bf16.
// ---------------------------------------------------------------------------
__global__ __launch_bounds__(256) void attn_kernel(
    const float* __restrict__ pkv,          // [BS][4608] packed q|k|v fp32
    unsigned short* __restrict__ ao)        // [BS][4096] bf16
{
  const int idx = blockIdx.x;
  const int qt = idx & 15;
  const int h  = (idx >> 4) & 15;
  const int g  = (idx >> 8) & 1;
  const int b  = idx >> 9;
  const int q0 = qt << 6;

  const float* qg = pkv + (size_t)b * S_LEN * QKV_N + (g * HPG + h) * DHEAD;
  const float* kg = pkv + (size_t)b * S_LEN * QKV_N + 4096 + g * DHEAD;
  const float* vg = pkv + (size_t)b * S_LEN * QKV_N + 4352 + g * DHEAD;

  __shared__ float Qs[64 * 128];
  __shared__ float Ks[64 * 128];
  __shared__ unsigned short Vs[64 * 128];   // total 80 KiB -> 2 blocks/CU

  const int tid = threadIdx.x, lane = tid & 63, w = tid >> 6;

#pragma unroll
  for (int i = 0; i < 8; ++i) {
    const int id = tid + (i << 8);
    const int r = id >> 5, c = id & 31;
    const float4 v4 = *(const float4*)(qg + (size_t)(q0 + r) * QKV_N + (c << 2));
    *(float4*)(Qs + r * 128 + ((c ^ (r & 7)) << 2)) = v4;
  }

  float m_[16], l_[16], o0_[16], o1_[16];
#pragma unroll
  for (int i = 0; i < 16; ++i) { m_[i] = -1e30f; l_[i] = 0.f; o0_[i] = 0.f; o1_[i] = 0.f; }

  const int d0 = lane << 1;                       // this lane owns dims d0, d0+1
  const float scale = 0.08838834764831845f;       // 1/sqrt(128)

#define SOFTMAX_ROW(SV, PV, RIDX) {                                            \
    float mt = SV;                                                             \
    mt = fmaxf(mt, __shfl_xor(mt, 32)); mt = fmaxf(mt, __shfl_xor(mt, 16));    \
    mt = fmaxf(mt, __shfl_xor(mt, 8));  mt = fmaxf(mt, __shfl_xor(mt, 4));     \
    mt = fmaxf(mt, __shfl_xor(mt, 2));  mt = fmaxf(mt, __shfl_xor(mt, 1));     \
    const float mnew = fmaxf(m_[RIDX], mt);                                    \
    PV = __expf(SV - mnew);                                                    \
    float ps = PV;                                                             \
    ps += __shfl_xor(ps, 32); ps += __shfl_xor(ps, 16); ps += __shfl_xor(ps, 8);\
    ps += __shfl_xor(ps, 4);  ps += __shfl_xor(ps, 2);  ps += __shfl_xor(ps, 1);\
    const float al = __expf(m_[RIDX] - mnew);                                  \
    m_[RIDX] = mnew; l_[RIDX] = l_[RIDX] * al + ps;                            \
    o0_[RIDX] *= al; o1_[RIDX] *= al; }

  for (int kt = 0; kt <= qt; ++kt) {
    const int kv0 = kt << 6;
    __syncthreads();
#pragma unroll
    for (int i = 0; i < 8; ++i) {
      const int id = tid + (i << 8);
      const int r = id >> 5, c = id & 31;
      const float4 v4 = *(const float4*)(kg + (size_t)(kv0 + r) * QKV_N + (c << 2));
      *(float4*)(Ks + r * 128 + ((c ^ (r & 7)) << 2)) = v4;
    }
#pragma unroll
    for (int i = 0; i < 8; ++i) {
      const int id = tid + (i << 8);
      const int r = id >> 5, c = id & 31;
      const float4 v4 = *(const float4*)(vg + (size_t)(kv0 + r) * QKV_N + (c << 2));
      u16x4 pk; pk.x = f2bf(v4.x); pk.y = f2bf(v4.y); pk.z = f2bf(v4.z); pk.w = f2bf(v4.w);
      *(u16x4*)(Vs + r * 128 + (c << 2)) = pk;
    }
    __syncthreads();

#pragma unroll
    for (int g4 = 0; g4 < 4; ++g4) {
      const int rl = (w << 4) + (g4 << 2);        // local first row of group
      const int grow = q0 + rl;
      float s0 = 0.f, s1 = 0.f, s2 = 0.f, s3 = 0.f;
#pragma unroll 4
      for (int c = 0; c < 32; ++c) {
        const float4 kv4 = *(const float4*)(Ks + lane * 128 + ((c ^ (lane & 7)) << 2));
        const float4 qa = *(const float4*)(Qs + (rl + 0) * 128 + ((c ^ ((rl + 0) & 7)) << 2));
        const float4 qb = *(const float4*)(Qs + (rl + 1) * 128 + ((c ^ ((rl + 1) & 7)) << 2));
        const float4 qc = *(const float4*)(Qs + (rl + 2) * 128 + ((c ^ ((rl + 2) & 7)) << 2));
        const float4 qd = *(const float4*)(Qs + (rl + 3) * 128 + ((c ^ ((rl + 3) & 7)) << 2));
        s0 = fmaf(kv4.x, qa.x, s0); s0 = fmaf(kv4.y, qa.y, s0);
        s0 = fmaf(kv4.z, qa.z, s0); s0 = fmaf(kv4.w, qa.w, s0);
        s1 = fmaf(kv4.x, qb.x, s1); s1 = fmaf(kv4.y, qb.y, s1);
        s1 = fmaf(kv4.z, qb.z, s1); s1 = fmaf(kv4.w, qb.w, s1);
        s2 = fmaf(kv4.x, qc.x, s2); s2 = fmaf(kv4.y, qc.y, s2);
        s2 = fmaf(kv4.z, qc.z, s2); s2 = fmaf(kv4.w, qc.w, s2);
        s3 = fmaf(kv4.x, qd.x, s3); s3 = fmaf(kv4.y, qd.y, s3);
        s3 = fmaf(kv4.z, qd.z, s3); s3 = fmaf(kv4.w, qd.w, s3);
      }
      const int jp = kv0 + lane;
      s0 = (jp <= grow + 0) ? s0 * scale : -1e30f;
      s1 = (jp <= grow + 1) ? s1 * scale : -1e30f;
      s2 = (jp <= grow + 2) ? s2 * scale : -1e30f;
      s3 = (jp <= grow + 3) ? s3 * scale : -1e30f;

      float p0, p1, p2, p3;
      SOFTMAX_ROW(s0, p0, g4 * 4 + 0)
      SOFTMAX_ROW(s1, p1, g4 * 4 + 1)
      SOFTMAX_ROW(s2, p2, g4 * 4 + 2)
      SOFTMAX_ROW(s3, p3, g4 * 4 + 3)

#pragma unroll 8
      for (int j = 0; j < 64; ++j) {
        const float pj0 = __shfl(p0, j);
        const float pj1 = __shfl(p1, j);
        const float pj2 = __shfl(p2, j);
        const float pj3 = __shfl(p3, j);
        const unsigned vv = *(const unsigned*)(Vs + j * 128 + d0);
        const float vlo = __uint_as_float(vv << 16);
        const float vhi = __uint_as_float(vv & 0xffff0000u);
        o0_[g4 * 4 + 0] = fmaf(pj0, vlo, o0_[g4 * 4 + 0]);
        o1_[g4 * 4 + 0] = fmaf(pj0, vhi, o1_[g4 * 4 + 0]);
        o0_[g4 * 4 + 1] = fmaf(pj1, vlo, o0_[g4 * 4 + 1]);
        o1_[g4 * 4 + 1] = fmaf(pj1, vhi, o1_[g4 * 4 + 1]);
        o0_[g4 * 4 + 2] = fmaf(pj2, vlo, o0_[g4 * 4 + 2]);
        o1_[g4 * 4 + 2] = fmaf(pj2, vhi, o1_[g4 * 4 + 2]);
        o0_[g4 * 4 + 3] = fmaf(pj3, vlo, o0_[g4 * 4 + 3]);
        o1_[g4 * 4 + 3] = fmaf(pj3, vhi, o1_[g4 * 4 + 3]);
      }
    }
  }

#pragma unroll
  for (int i = 0; i < 16; ++i) {
    const int grow = q0 + (w << 4) + i;
    const float inv = 1.f / l_[i];
    const unsigned lo = f2bf(o0_[i] * inv);
    const unsigned hi = f2bf(o1_[i] * inv);
    *(unsigned*)(ao + (size_t)(b * S_LEN + grow) * HDIM + (g * HPG + h) * DHEAD + d0)
        = (hi << 16) | lo;
  }
#undef SOFTMAX_ROW
}

// ---------------------------------------------------------------------------
extern "C" void kernel_launch(void* const* d_in, const int* in_sizes, int n_in,
                              void* d_out, int out_size, void* d_ws, size_t ws_size,
                              hipStream_t stream)
{
  const float* x   = (const float*)d_in[0];
  const float* g1  = (const float*)d_in[1];
  const float* b1  = (const float*)d_in[2];
  const float* wq  = (const float*)d_in[3];
  const float* bq  = (const float*)d_in[4];
  const float* wk  = (const float*)d_in[5];
  const float* bk  = (const float*)d_in[6];
  const float* wv  = (const float*)d_in[7];
  const float* bv  = (const float*)d_in[8];
  const float* wo  = (const float*)d_in[9];
  const float* bo  = (const float*)d_in[10];
  const float* g2  = (const float*)d_in[11];
  const float* b2  = (const float*)d_in[12];
  const float* wup = (const float*)d_in[13];
  const float* bup = (const float*)d_in[14];
  const float* wdn = (const float*)d_in[15];
  const float* bdn = (const float*)d_in[16];

  char* p = (char*)d_ws;
  auto alloc = [&](size_t bytes) { char* r = p; p += (bytes + 255) & ~(size_t)255; return (void*)r; };
  float*          x1f   = (float*)alloc((size_t)BS * HDIM * 4);
  unsigned short* x1b   = (unsigned short*)alloc((size_t)BS * HDIM * 2);
  float*          pkv   = (float*)alloc((size_t)BS * QKV_N * 4);
  unsigned short* aob   = (unsigned short*)alloc((size_t)BS * HDIM * 2);
  unsigned short* x2b   = (unsigned short*)alloc((size_t)BS * HDIM * 2);
  unsigned short* hb    = (unsigned short*)alloc((size_t)BS * FFN * 2);
  unsigned short* wqkvt = (unsigned short*)alloc((size_t)QKV_N * HDIM * 2);
  unsigned short* wot   = (unsigned short*)alloc((size_t)HDIM * HDIM * 2);
  unsigned short* wupt  = (unsigned short*)alloc((size_t)FFN * HDIM * 2);
  unsigned short* wdnt  = (unsigned short*)alloc((size_t)HDIM * FFN * 2);
  float*          bqkv  = (float*)alloc((size_t)QKV_N * 4);
  float*          po    = (float*)d_out;   // reuse d_out as attn-proj scratch

  const size_t need = (size_t)(p - (char*)d_ws);
  if (need > ws_size) return;              // ~529 MB required; bail cleanly if not

  // weight prep (re-done every call; inputs re-poisoned between timed calls)
  transpose_cvt_kernel<<<dim3(128, 128), 256, 0, stream>>>(wq, wqkvt, HDIM, HDIM);
  transpose_cvt_kernel<<<dim3(8, 128),   256, 0, stream>>>(wk, wqkvt + (size_t)4096 * HDIM, HDIM, 256);
  transpose_cvt_kernel<<<dim3(8, 128),   256, 0, stream>>>(wv, wqkvt + (size_t)4352 * HDIM, HDIM, 256);
  transpose_cvt_kernel<<<dim3(128, 128), 256, 0, stream>>>(wo, wot, HDIM, HDIM);
  transpose_cvt_kernel<<<dim3(512, 128), 256, 0, stream>>>(wup, wupt, HDIM, FFN);
  transpose_cvt_kernel<<<dim3(128, 512), 256, 0, stream>>>(wdn, wdnt, FFN, HDIM);
  pack_bias_kernel<<<18, 256, 0, stream>>>(bq, bk, bv, bqkv);

  // x1 = x + LN1(x)
  ln_res_kernel<<<BS, 256, 0, stream>>>(x, x, g1, b1, x1f, x1b);
  // packed q|k|v = x1 @ [wq|wk|wv] + [bq|bk|bv]
  gemm_kernel<0, 1, 0><<<dim3(36, 16), 256, 0, stream>>>(x1b, wqkvt, bqkv, pkv, nullptr, BS, QKV_N, HDIM);
  // causal GQA attention
  attn_kernel<<<1024, 256, 0, stream>>>(pkv, aob);
  // attn out projection
  gemm_kernel<0, 1, 0><<<dim3(32, 16), 256, 0, stream>>>(aob, wot, bo, po, nullptr, BS, HDIM, HDIM);
  // x2 = x1 + LN2(attn_proj)
  ln_res_kernel<<<BS, 256, 0, stream>>>(x1f, po, g2, b2, nullptr, x2b);
  // MLP up + exact GELU
  gemm_kernel<1, 0, 1><<<dim3(128, 16), 256, 0, stream>>>(x2b, wupt, bup, nullptr, hb, BS, FFN, HDIM);
  // MLP down -> d_out (fully overwrites the po scratch)
  gemm_kernel<0, 1, 0><<<dim3(32, 16), 256, 0, stream>>>(hb, wdnt, bdn, (float*)d_out, nullptr, BS, HDIM, FFN);
}

// Round 2
// 1962.931 us; speedup vs baseline: 1.5303x; 1.5303x over previous
//
#include <hip/hip_runtime.h>
#include <stdint.h>

// Problem constants (B=2, S=1024, H=4096, NH=32, G=2, D=128, HG=16)
#define S_LEN 1024
#define HDIM  4096
#define BS    2048          // B * S
#define DHEAD 128
#define HPG   16            // heads per group
#define QKV_N 4608          // 4096 (q) + 256 (k) + 256 (v)
#define FFN   16384

typedef __attribute__((ext_vector_type(8))) short bf16x8;
typedef __attribute__((ext_vector_type(4))) float f32x4;
typedef __attribute__((ext_vector_type(4))) unsigned short u16x4;

__device__ __forceinline__ unsigned short f2bf(float f) {
  union { float f; unsigned u; } c; c.f = f;
  return (unsigned short)((c.u + 0x7fffu + ((c.u >> 16) & 1u)) >> 16);  // RNE
}

// async 16B global->LDS copy (gfx950). LDS dest must be wave-base + lane*16.
__device__ __forceinline__ void gld_lds16(const void* g, void* l) {
  __builtin_amdgcn_global_load_lds(
      (const __attribute__((address_space(1))) void*)g,
      (__attribute__((address_space(3))) void*)l, 16, 0, 0);
}

// ---------------------------------------------------------------------------
// out = res + LN(inp)*g + b ; optional fp32 and bf16 outputs
// ---------------------------------------------------------------------------
__global__ __launch_bounds__(256) void ln_res_kernel(
    const float* __restrict__ res, const float* __restrict__ inp,
    const float* __restrict__ gam, const float* __restrict__ bet,
    float* __restrict__ of, unsigned short* __restrict__ ob)
{
  const int row = blockIdx.x;
  const int tid = threadIdx.x;
  const float* ip = inp + (size_t)row * HDIM;
  const float* rp = res + (size_t)row * HDIM;

  float4 xv[4];
  float s = 0.f, ss = 0.f;
#pragma unroll
  for (int i = 0; i < 4; ++i) {
    xv[i] = *(const float4*)(ip + ((i * 256 + tid) << 2));
    s  += xv[i].x + xv[i].y + xv[i].z + xv[i].w;
    ss += xv[i].x * xv[i].x + xv[i].y * xv[i].y + xv[i].z * xv[i].z + xv[i].w * xv[i].w;
  }
#pragma unroll
  for (int off = 32; off; off >>= 1) {
    s  += __shfl_xor(s, off);
    ss += __shfl_xor(ss, off);
  }
  __shared__ float red[8];
  if ((tid & 63) == 0) { red[(tid >> 6) * 2] = s; red[(tid >> 6) * 2 + 1] = ss; }
  __syncthreads();
  s  = red[0] + red[2] + red[4] + red[6];
  ss = red[1] + red[3] + red[5] + red[7];
  const float mu   = s * (1.f / HDIM);
  const float rstd = rsqrtf(ss * (1.f / HDIM) - mu * mu + 1e-5f);

#pragma unroll
  for (int i = 0; i < 4; ++i) {
    const int e = (i * 256 + tid) << 2;
    const float4 gv = *(const float4*)(gam + e);
    const float4 bv = *(const float4*)(bet + e);
    const float4 rv = *(const float4*)(rp + e);
    float4 o;
    o.x = rv.x + (xv[i].x - mu) * rstd * gv.x + bv.x;
    o.y = rv.y + (xv[i].y - mu) * rstd * gv.y + bv.y;
    o.z = rv.z + (xv[i].z - mu) * rstd * gv.z + bv.z;
    o.w = rv.w + (xv[i].w - mu) * rstd * gv.w + bv.w;
    if (of) *(float4*)(of + (size_t)row * HDIM + e) = o;
    if (ob) {
      u16x4 pk; pk.x = f2bf(o.x); pk.y = f2bf(o.y); pk.z = f2bf(o.z); pk.w = f2bf(o.w);
      *(u16x4*)(ob + (size_t)row * HDIM + e) = pk;
    }
  }
}

// ---------------------------------------------------------------------------
// W [K][N] fp32  ->  Wt [N][K] bf16   (32x32 tiles via LDS)
// ---------------------------------------------------------------------------
__global__ __launch_bounds__(256) void transpose_cvt_kernel(
    const float* __restrict__ W, unsigned short* __restrict__ Wt,
    const int K, const int N)
{
  __shared__ float t[32][36];
  const int n0 = blockIdx.x << 5, k0 = blockIdx.y << 5;
  const int tx4 = threadIdx.x & 7, ty = threadIdx.x >> 3;
  const float4 v4 = *(const float4*)(W + (size_t)(k0 + ty) * N + n0 + (tx4 << 2));
  *(float4*)&t[ty][tx4 << 2] = v4;
  __syncthreads();
  u16x4 o;
  o.x = f2bf(t[(tx4 << 2) + 0][ty]);
  o.y = f2bf(t[(tx4 << 2) + 1][ty]);
  o.z = f2bf(t[(tx4 << 2) + 2][ty]);
  o.w = f2bf(t[(tx4 << 2) + 3][ty]);
  *(u16x4*)(Wt + (size_t)(n0 + ty) * K + k0 + (tx4 << 2)) = o;
}

__global__ __launch_bounds__(256) void pack_bias_kernel(
    const float* __restrict__ bq, const float* __restrict__ bk,
    const float* __restrict__ bv, float* __restrict__ out)
{
  const int i = blockIdx.x * 256 + threadIdx.x;
  float v;
  if (i < 4096)       v = bq[i];
  else if (i < 4352)  v = bk[i - 4096];
  else                v = bv[i - 4352];
  out[i] = v;
}

// ---------------------------------------------------------------------------
// C[M][N] = A[M][K] @ Bt[N][K]^T + bias ; optional GELU ; fp32/bf16 stores
// 128x128 tile, BK=32, 4 waves, global_load_lds staging (m97 structure).
// ---------------------------------------------------------------------------
template<int DO_GELU, int ST_F32, int ST_BF16>
__global__ __launch_bounds__(256) void gemm_kernel(
    const unsigned short* __restrict__ A,
    const unsigned short* __restrict__ Bt,
    const float* __restrict__ bias,
    float* __restrict__ Cf, unsigned short* __restrict__ Cb,
    const int M, const int N, const int K)
{
  __shared__ unsigned short As[128 * 32];
  __shared__ unsigned short Bs[128 * 32];
  const int tid  = threadIdx.x;
  const int lane = tid & 63;
  const int w = tid >> 6, wm = w >> 1, wn = w & 1;
  const int bm = blockIdx.y << 7, bn = blockIdx.x << 7;
  const int fr = lane & 15, kq = lane >> 4;

  const unsigned short* Ag = A  + (size_t)bm * K;
  const unsigned short* Bg = Bt + (size_t)bn * K;
  const int r0 = tid >> 2, k0e = (tid & 3) << 3;   // row, 16B k-chunk
  const int r1 = r0 + 64;

  f32x4 acc[4][4] = {};

  const int KT = K >> 5;
  for (int kt = 0; kt < KT; ++kt) {
    const int ko = kt << 5;
    __syncthreads();   // all waves done reading previous tile
    gld_lds16(Ag + (size_t)r0 * K + ko + k0e, As + (size_t)tid * 8);
    gld_lds16(Ag + (size_t)r1 * K + ko + k0e, As + 2048 + (size_t)tid * 8);
    gld_lds16(Bg + (size_t)r0 * K + ko + k0e, Bs + (size_t)tid * 8);
    gld_lds16(Bg + (size_t)r1 * K + ko + k0e, Bs + 2048 + (size_t)tid * 8);
    __syncthreads();   // vmcnt(0) drained before barrier -> tile ready

    bf16x8 af[4], bfr[4];
#pragma unroll
    for (int i = 0; i < 4; ++i) {
      af[i]  = *(const bf16x8*)(As + (wm * 64 + i * 16 + fr) * 32 + (kq << 3));
      bfr[i] = *(const bf16x8*)(Bs + (wn * 64 + i * 16 + fr) * 32 + (kq << 3));
    }
#pragma unroll
    for (int mi = 0; mi < 4; ++mi)
#pragma unroll
      for (int ni = 0; ni < 4; ++ni)
        acc[mi][ni] = __builtin_amdgcn_mfma_f32_16x16x32_bf16(af[mi], bfr[ni], acc[mi][ni], 0, 0, 0);
  }

#pragma unroll
  for (int mi = 0; mi < 4; ++mi) {
#pragma unroll
    for (int ni = 0; ni < 4; ++ni) {
      const int col = bn + wn * 64 + ni * 16 + fr;
      const float bv = bias[col];
#pragma unroll
      for (int r = 0; r < 4; ++r) {
        const int row = bm + wm * 64 + mi * 16 + kq * 4 + r;
        float v = acc[mi][ni][r] + bv;
        if (DO_GELU) v = 0.5f * v * (1.f + erff(v * 0.7071067811865476f));
        if (ST_F32)  Cf[(size_t)row * N + col] = v;
        if (ST_BF16) Cb[(size_t)row * N + col] = f2bf(v);
      }
    }
  }
}

// ---------------------------------------------------------------------------
// Causal GQA flash attention with MFMA (bf16 inputs, fp32 softmax).
// Block = (b, g, h, 64-row q tile); 4 waves x 16 q-rows each; KV tiles of 64.
// LDS: Ks[64][128] (chunk^row&7 swizzled, filled via pre-swizzled gld_lds),
//      Vt[128][64] (transposed V, swizzled), Ps[wave][16][64] (swizzled).
// ---------------------------------------------------------------------------
__global__ __launch_bounds__(256, 4) void attn_kernel(
    const unsigned short* __restrict__ pkv,   // [BS][4608] packed q|k|v bf16
    unsigned short* __restrict__ ao)          // [BS][4096] bf16
{
  const int idx = blockIdx.x;
  const int qt = idx & 15;
  const int h  = (idx >> 4) & 15;
  const int g  = (idx >> 8) & 1;
  const int b  = idx >> 9;
  const int q0 = qt << 6;

  const unsigned short* qg = pkv + (size_t)b * S_LEN * QKV_N + (g * HPG + h) * DHEAD;
  const unsigned short* kg = pkv + (size_t)b * S_LEN * QKV_N + 4096 + g * DHEAD;
  const unsigned short* vg = pkv + (size_t)b * S_LEN * QKV_N + 4352 + g * DHEAD;

  __shared__ unsigned short Ks[64 * 128];    // 16 KiB
  __shared__ unsigned short Vt[128 * 64];    // 16 KiB
  __shared__ unsigned short Ps[4][16 * 64];  //  8 KiB

  const int tid = threadIdx.x, lane = tid & 63, w = tid >> 6;
  const int c15 = lane & 15, q4 = lane >> 4;

  // Q fragments in registers: a_q[kk] = Q[w*16 + c15][kk*32 + q4*8 .. +8]
  bf16x8 a_q[4];
  {
    const unsigned short* qrow = qg + (size_t)(q0 + w * 16 + c15) * QKV_N;
#pragma unroll
    for (int kk = 0; kk < 4; ++kk)
      a_q[kk] = *(const bf16x8*)(qrow + kk * 32 + (q4 << 3));
  }

  f32x4 oacc[8] = {};
  float m_[4], l_[4];
#pragma unroll
  for (int r = 0; r < 4; ++r) { m_[r] = -1e30f; l_[r] = 0.f; }

  const float scale = 0.08838834764831845f;   // 1/sqrt(128)

  for (int kt = 0; kt <= qt; ++kt) {
    const int kv0 = kt << 6;
    __syncthreads();                          // everyone done with prev K/Vt

    // stage K: LDS[r][ch] = K[kv0+r][ (ch ^ (r&7))*8 .. ] -> read-side XOR undoes it
#pragma unroll
    for (int i = 0; i < 4; ++i) {
      const int id = tid + (i << 8);          // 0..1023 16B-chunks
      const int r = id >> 4, ch = id & 15;
      gld_lds16(kg + (size_t)(kv0 + r) * QKV_N + ((ch ^ (r & 7)) << 3),
                Ks + (size_t)id * 8);
    }
    // stage V transposed: Vt[dim][kv] (u32 = 2 kv per write), swizzled
#pragma unroll
    for (int i = 0; i < 4; ++i) {
      const int dq = (tid >> 5) + (i << 3);   // dim quad 0..31
      const int kp = tid & 31;                // kv pair
      const u16x4 va = *(const u16x4*)(vg + (size_t)(kv0 + 2 * kp) * QKV_N + (dq << 2));
      const u16x4 vb = *(const u16x4*)(vg + (size_t)(kv0 + 2 * kp + 1) * QKV_N + (dq << 2));
#pragma unroll
      for (int d = 0; d < 4; ++d) {
        const int dim = (dq << 2) + d;
        const unsigned pk = ((unsigned)vb[d] << 16) | (unsigned)va[d];
        *(unsigned*)(Vt + dim * 64 + (((kp >> 2) ^ (dim & 7)) << 3) + ((2 * kp) & 7)) = pk;
      }
    }
    __syncthreads();                          // staging complete (vmcnt drained)

    // ---- QK^T: sacc[nt] = S[q-rows][nt*16 + c15] ----
    f32x4 sacc[4] = {};
#pragma unroll
    for (int kk = 0; kk < 4; ++kk) {
#pragma unroll
      for (int nt = 0; nt < 4; ++nt) {
        const int kr = nt * 16 + c15;
        const bf16x8 bk = *(const bf16x8*)(Ks + kr * 128 + ((((kk << 2) + q4) ^ (kr & 7)) << 3));
        sacc[nt] = __builtin_amdgcn_mfma_f32_16x16x32_bf16(a_q[kk], bk, sacc[nt], 0, 0, 0);
      }
    }

    // ---- online softmax (rows = q4*4 + r), P -> per-wave LDS (bf16) ----
    const int diag = (kt == qt);
#pragma unroll
    for (int r = 0; r < 4; ++r) {
      const int qrow = q0 + w * 16 + (q4 << 2) + r;
      float s_[4];
#pragma unroll
      for (int nt = 0; nt < 4; ++nt) {
        s_[nt] = sacc[nt][r] * scale;
        if (diag && (kv0 + nt * 16 + c15 > qrow)) s_[nt] = -1e30f;
      }
      float mt = fmaxf(fmaxf(s_[0], s_[1]), fmaxf(s_[2], s_[3]));
      mt = fmaxf(mt, __shfl_xor(mt, 1));
      mt = fmaxf(mt, __shfl_xor(mt, 2));
      mt = fmaxf(mt, __shfl_xor(mt, 4));
      mt = fmaxf(mt, __shfl_xor(mt, 8));
      const float mnew = fmaxf(m_[r], mt);
      const float al = __expf(m_[r] - mnew);
      float p_[4], ps = 0.f;
#pragma unroll
      for (int nt = 0; nt < 4; ++nt) { p_[nt] = __expf(s_[nt] - mnew); ps += p_[nt]; }
      ps += __shfl_xor(ps, 1);
      ps += __shfl_xor(ps, 2);
      ps += __shfl_xor(ps, 4);
      ps += __shfl_xor(ps, 8);
      l_[r] = l_[r] * al + ps;
      m_[r] = mnew;
#pragma unroll
      for (int ont = 0; ont < 8; ++ont) oacc[ont][r] *= al;

      const int prow = (q4 << 2) + r;
#pragma unroll
      for (int nt = 0; nt < 4; ++nt) {
        const int col = nt * 16 + c15;
        Ps[w][prow * 64 + (((col >> 3) ^ (prow & 7)) << 3) + (col & 7)] = f2bf(p_[nt]);
      }
    }

    // ---- PV: oacc[ont] += P @ V ----
    bf16x8 a_p[2];
#pragma unroll
    for (int kk = 0; kk < 2; ++kk)
      a_p[kk] = *(const bf16x8*)(&Ps[w][c15 * 64 + ((((kk << 2) + q4) ^ (c15 & 7)) << 3)]);
#pragma unroll
    for (int ont = 0; ont < 8; ++ont) {
#pragma unroll
      for (int kk = 0; kk < 2; ++kk) {
        const int vr = ont * 16 + c15;
        const bf16x8 bv = *(const bf16x8*)(Vt + vr * 64 + ((((kk << 2) + q4) ^ (vr & 7)) << 3));
        oacc[ont] = __builtin_amdgcn_mfma_f32_16x16x32_bf16(a_p[kk], bv, oacc[ont], 0, 0, 0);
      }
    }
  }

  // ---- epilogue: normalize and store bf16 ----
#pragma unroll
  for (int r = 0; r < 4; ++r) {
    const float inv = 1.f / l_[r];
    const int qrow = q0 + w * 16 + (q4 << 2) + r;
    unsigned short* orow = ao + (size_t)(b * S_LEN + qrow) * HDIM + (g * HPG + h) * DHEAD;
#pragma unroll
    for (int ont = 0; ont < 8; ++ont)
      orow[ont * 16 + c15] = f2bf(oacc[ont][r] * inv);
  }
}

// ---------------------------------------------------------------------------
extern "C" void kernel_launch(void* const* d_in, const int* in_sizes, int n_in,
                              void* d_out, int out_size, void* d_ws, size_t ws_size,
                              hipStream_t stream)
{
  const float* x   = (const float*)d_in[0];
  const float* g1  = (const float*)d_in[1];
  const float* b1  = (const float*)d_in[2];
  const float* wq  = (const float*)d_in[3];
  const float* bq  = (const float*)d_in[4];
  const float* wk  = (const float*)d_in[5];
  const float* bk  = (const float*)d_in[6];
  const float* wv  = (const float*)d_in[7];
  const float* bv  = (const float*)d_in[8];
  const float* wo  = (const float*)d_in[9];
  const float* bo  = (const float*)d_in[10];
  const float* g2  = (const float*)d_in[11];
  const float* b2  = (const float*)d_in[12];
  const float* wup = (const float*)d_in[13];
  const float* bup = (const float*)d_in[14];
  const float* wdn = (const float*)d_in[15];
  const float* bdn = (const float*)d_in[16];

  char* p = (char*)d_ws;
  auto alloc = [&](size_t bytes) { char* r = p; p += (bytes + 255) & ~(size_t)255; return (void*)r; };
  float*          x1f   = (float*)alloc((size_t)BS * HDIM * 4);
  unsigned short* x1b   = (unsigned short*)alloc((size_t)BS * HDIM * 2);
  unsigned short* pkvb  = (unsigned short*)alloc((size_t)BS * QKV_N * 2);
  unsigned short* aob   = (unsigned short*)alloc((size_t)BS * HDIM * 2);
  unsigned short* x2b   = (unsigned short*)alloc((size_t)BS * HDIM * 2);
  unsigned short* hb    = (unsigned short*)alloc((size_t)BS * FFN * 2);
  unsigned short* wqkvt = (unsigned short*)alloc((size_t)QKV_N * HDIM * 2);
  unsigned short* wot   = (unsigned short*)alloc((size_t)HDIM * HDIM * 2);
  unsigned short* wupt  = (unsigned short*)alloc((size_t)FFN * HDIM * 2);
  unsigned short* wdnt  = (unsigned short*)alloc((size_t)HDIM * FFN * 2);
  float*          bqkv  = (float*)alloc((size_t)QKV_N * 4);
  float*          po    = (float*)d_out;   // reuse d_out as attn-proj scratch

  const size_t need = (size_t)(p - (char*)d_ws);
  if (need > ws_size) return;

  // weight prep (re-done every call)
  transpose_cvt_kernel<<<dim3(128, 128), 256, 0, stream>>>(wq, wqkvt, HDIM, HDIM);
  transpose_cvt_kernel<<<dim3(8, 128),   256, 0, stream>>>(wk, wqkvt + (size_t)4096 * HDIM, HDIM, 256);
  transpose_cvt_kernel<<<dim3(8, 128),   256, 0, stream>>>(wv, wqkvt + (size_t)4352 * HDIM, HDIM, 256);
  transpose_cvt_kernel<<<dim3(128, 128), 256, 0, stream>>>(wo, wot, HDIM, HDIM);
  transpose_cvt_kernel<<<dim3(512, 128), 256, 0, stream>>>(wup, wupt, HDIM, FFN);
  transpose_cvt_kernel<<<dim3(128, 512), 256, 0, stream>>>(wdn, wdnt, FFN, HDIM);
  pack_bias_kernel<<<18, 256, 0, stream>>>(bq, bk, bv, bqkv);

  // x1 = x + LN1(x)
  ln_res_kernel<<<BS, 256, 0, stream>>>(x, x, g1, b1, x1f, x1b);
  // packed q|k|v (bf16) = x1 @ [wq|wk|wv] + [bq|bk|bv]
  gemm_kernel<0, 0, 1><<<dim3(36, 16), 256, 0, stream>>>(x1b, wqkvt, bqkv, nullptr, pkvb, BS, QKV_N, HDIM);
  // causal GQA attention (MFMA)
  attn_kernel<<<1024, 256, 0, stream>>>(pkvb, aob);
  // attn out projection
  gemm_kernel<0, 1, 0><<<dim3(32, 16), 256, 0, stream>>>(aob, wot, bo, po, nullptr, BS, HDIM, HDIM);
  // x2 = x1 + LN2(attn_proj)
  ln_res_kernel<<<BS, 256, 0, stream>>>(x1f, po, g2, b2, nullptr, x2b);
  // MLP up + exact GELU
  gemm_kernel<1, 0, 1><<<dim3(128, 16), 256, 0, stream>>>(x2b, wupt, bup, nullptr, hb, BS, FFN, HDIM);
  // MLP down -> d_out
  gemm_kernel<0, 1, 0><<<dim3(32, 16), 256, 0, stream>>>(hb, wdnt, bdn, (float*)d_out, nullptr, BS, HDIM, FFN);
}